// Round 2
// baseline (1328.842 us; speedup 1.0000x reference)
//
#include <hip/hip_runtime.h>
#include <cstdint>
#include <cstddef>

typedef __attribute__((ext_vector_type(4))) float f32x4;
typedef __attribute__((ext_vector_type(8))) __bf16 bf16x8;
typedef __attribute__((ext_vector_type(8))) short short8;

__device__ __forceinline__ unsigned short f2bf(float f) {
  unsigned u = __builtin_bit_cast(unsigned, f);
  u += 0x7FFFu + ((u >> 16) & 1u);  // RNE
  return (unsigned short)(u >> 16);
}
__device__ __forceinline__ unsigned pack2(float a, float b) {
  return (unsigned)f2bf(a) | ((unsigned)f2bf(b) << 16);
}

// async 16B global->LDS (wave-uniform base + lane*16; our per-lane addrs satisfy this)
__device__ __forceinline__ void async16(const void* g, void* l) {
  __builtin_amdgcn_global_load_lds((const __attribute__((address_space(1))) unsigned int*)g,
                                   (__attribute__((address_space(3))) unsigned int*)l, 16, 0, 0);
}

// ---------------------------------------------------------------------------
// Grid-wide barrier: monotone arrival counter, device-scope. Safe because the
// grid is sized to guaranteed co-residency (occupancy query, host side).
// ---------------------------------------------------------------------------
__device__ __forceinline__ void grid_barrier(unsigned* bar, int stage, int nblk) {
  __threadfence();      // release: make this block's writes device-visible
  __syncthreads();
  if (threadIdx.x == 0) {
    atomicAdd(bar, 1u);  // device-scope arrival
    const unsigned tgt = (unsigned)stage * (unsigned)nblk;
    while (__hip_atomic_load(bar, __ATOMIC_ACQUIRE, __HIP_MEMORY_SCOPE_AGENT) < tgt)
      __builtin_amdgcn_s_sleep(8);
  }
  __syncthreads();
  __threadfence();      // acquire: invalidate so we see other XCDs' writes
}

// ---------------------------------------------------------------------------
// GEMM body: C[128,N](fp32, +bias on kseg0) = A[128,K](bf16) @ W[N,K](fp32)^T
// A staged via global_load_lds into XOR-swizzled LDS (cc = c ^ (r&7), 16B chunks).
// W loaded to regs one tile ahead (latency cover), converted, ds_written.
// LDS comes from the caller's pool (a_pool: 2*128*64 shorts, w_pool: 2*BN*64).
// ---------------------------------------------------------------------------
struct GemmArgs {
  const unsigned short* A;  // bf16 [128, lda]
  const float* W;           // fp32 [N, ldw]
  const float* bias;        // [N]
  float* C;                 // fp32 [128, N] at C + kseg*seg_stride
};

template <int BN, int WAVES_M, int WAVES_N>
__device__ __forceinline__ void gemm_body(const GemmArgs g, int bx, int bz, int lda, int ldw,
                                          int N, int Kseg, int seg_stride,
                                          unsigned short* a_pool, unsigned short* w_pool) {
  constexpr int WM = 128 / WAVES_M, WN = BN / WAVES_N;
  constexpr int MT = WM / 16, NT = WN / 16;
  constexpr int ASTRIDE = 128 * 64, WSTRIDE = BN * 64;

  const int kbase = bz * Kseg;
  const int tid = threadIdx.x;
  const int wave = tid >> 6, lane = tid & 63;
  const int quad = lane >> 4, l16 = lane & 15;
  const int n0 = bx * BN;
  const int wm = (wave / WAVES_N) * WM, wn = (wave % WAVES_N) * WN;
  const int niter = Kseg >> 6;

  f32x4 wv[2];

  auto stageA = [&](int k0, int buf) {
    unsigned short* dst = a_pool + buf * ASTRIDE;
#pragma unroll
    for (int i = 0; i < 4; ++i) {
      int chunk = (wave * 4 + i) * 64 + lane;          // 1024 chunks = 128 rows x 8
      int r = chunk >> 3;
      int c = (chunk & 7) ^ (r & 7);                   // logical 16B-chunk for this slot
      async16(g.A + (size_t)r * lda + (k0 + c * 8), dst + chunk * 8);
    }
  };
  auto loadW = [&](int k0) {
    if constexpr (BN == 32) {
      const float* p = g.W + (size_t)(n0 + (tid >> 3)) * ldw + k0 + (tid & 7) * 8;
      wv[0] = *(const f32x4*)p;
      wv[1] = *(const f32x4*)(p + 4);
    } else {
      const float* p = g.W + (size_t)(n0 + (tid >> 4)) * ldw + k0 + ((tid >> 1) & 7) * 8 + (tid & 1) * 4;
      wv[0] = *(const f32x4*)p;
    }
  };
  auto writeW = [&](int buf) {
    unsigned short* dst = w_pool + buf * WSTRIDE;
    if constexpr (BN == 32) {
      int wr = tid >> 3, wc = tid & 7;
      uint4 pk{pack2(wv[0].x, wv[0].y), pack2(wv[0].z, wv[0].w),
               pack2(wv[1].x, wv[1].y), pack2(wv[1].z, wv[1].w)};
      *(uint4*)&dst[(wr * 8 + (wc ^ (wr & 7))) * 8] = pk;
    } else {
      int wr = tid >> 4, wc = (tid >> 1) & 7, half = tid & 1;
      uint2 pk{pack2(wv[0].x, wv[0].y), pack2(wv[0].z, wv[0].w)};
      *(uint2*)&dst[(wr * 8 + (wc ^ (wr & 7))) * 8 + half * 4] = pk;
    }
  };

  f32x4 acc[MT][NT] = {};

  stageA(kbase, 0);
  loadW(kbase);
  writeW(0);
  __syncthreads();

  for (int ki = 0; ki < niter; ++ki) {
    const int cur = ki & 1;
    const bool more = (ki + 1 < niter);
    if (more) {
      stageA(kbase + (ki + 1) * 64, cur ^ 1);   // async into other buffer
      loadW(kbase + (ki + 1) * 64);             // in flight across MFMA phase
    }
    const unsigned short* ab = a_pool + cur * ASTRIDE;
    const unsigned short* wb = w_pool + cur * WSTRIDE;
#pragma unroll
    for (int kh = 0; kh < 2; ++kh) {
      const int c = kh * 4 + quad;
      bf16x8 af[MT], wf[NT];
#pragma unroll
      for (int mt = 0; mt < MT; ++mt) {
        int m = wm + mt * 16 + l16;
        af[mt] = __builtin_bit_cast(bf16x8, *(const short8*)&ab[(m * 8 + (c ^ (m & 7))) * 8]);
      }
#pragma unroll
      for (int nt = 0; nt < NT; ++nt) {
        int n = wn + nt * 16 + l16;
        wf[nt] = __builtin_bit_cast(bf16x8, *(const short8*)&wb[(n * 8 + (c ^ (n & 7))) * 8]);
      }
#pragma unroll
      for (int mt = 0; mt < MT; ++mt)
#pragma unroll
        for (int nt = 0; nt < NT; ++nt)
          acc[mt][nt] = __builtin_amdgcn_mfma_f32_16x16x32_bf16(af[mt], wf[nt], acc[mt][nt], 0, 0, 0);
    }
    if (more) writeW(cur ^ 1);
    __syncthreads();
  }

  float* C = g.C + (size_t)bz * seg_stride;
#pragma unroll
  for (int mt = 0; mt < MT; ++mt)
#pragma unroll
    for (int nt = 0; nt < NT; ++nt) {
      int n = n0 + wn + nt * 16 + l16;
      float bv = (bz == 0) ? g.bias[n] : 0.f;
#pragma unroll
      for (int r = 0; r < 4; ++r) {
        int m = wm + mt * 16 + quad * 4 + r;
        C[(size_t)m * N + n] = acc[mt][nt][r] + bv;
      }
    }
}

// ---------------------------------------------------------------------------
// prep: bf16 copies of embed[ids] (A0), hidden[0] (Hh0), hidden[1] (Hh1)
// ---------------------------------------------------------------------------
__device__ __forceinline__ void prep_body(int b, const int* __restrict__ ids,
                                          const float* __restrict__ hidden,
                                          const float* __restrict__ embed,
                                          unsigned short* A0, unsigned short* Hh0,
                                          unsigned short* Hh1) {
  int job = b >> 7, m = b & 127, t = threadIdx.x;
  const float* src;
  unsigned short* dst;
  if (job == 0) { src = embed + (size_t)ids[m] * 1024; dst = A0; }
  else if (job == 1) { src = hidden + (size_t)m * 1024; dst = Hh0; }
  else { src = hidden + 131072 + (size_t)m * 1024; dst = Hh1; }
  f32x4 v = ((const f32x4*)src)[t];
  uint2 pk{pack2(v.x, v.y), pack2(v.z, v.w)};
  *(uint2*)(dst + (size_t)m * 1024 + t * 4) = pk;
}

// ---------------------------------------------------------------------------
// u2[e] = sum_h v[h] * W_attn[h, 1024+e]  (h-half + b_attn are softmax-invariant)
// ---------------------------------------------------------------------------
__device__ __forceinline__ void u2_body(int b, const float* __restrict__ W_attn,
                                        const float* __restrict__ v, float* __restrict__ u2) {
  int eb = b & 3, hc = b >> 2;
  int e = eb * 256 + threadIdx.x;
  float acc = 0.f;
  int h0 = hc * 32;
#pragma unroll 4
  for (int h = h0; h < h0 + 32; ++h) acc += v[h] * W_attn[(size_t)h * 2048 + 1024 + e];
  atomicAdd(u2 + e, acc);
}

// ---------------------------------------------------------------------------
// scores_t[b,s] = enc[s,b,:] . u2 ; per wave 4 rows, 2 load phases (reg-lean)
// ---------------------------------------------------------------------------
__device__ __forceinline__ void scores_body(int b, const float* __restrict__ enc,
                                            const float* __restrict__ u2,
                                            float* __restrict__ sct) {
  int wave = threadIdx.x >> 6, lane = threadIdx.x & 63;
  const f32x4* u4 = (const f32x4*)u2;
  int row0 = (b * 4 + wave) * 4;
  const f32x4* base = (const f32x4*)enc;
  float a[4] = {0.f, 0.f, 0.f, 0.f};
#pragma unroll
  for (int ph = 0; ph < 2; ++ph) {
    f32x4 uv[2], ev[4][2];
#pragma unroll
    for (int p = 0; p < 2; ++p) uv[p] = u4[(ph * 2 + p) * 64 + lane];
#pragma unroll
    for (int r = 0; r < 4; ++r)
#pragma unroll
      for (int p = 0; p < 2; ++p)
        ev[r][p] = base[(size_t)(row0 + r) * 256 + (ph * 2 + p) * 64 + lane];
#pragma unroll
    for (int r = 0; r < 4; ++r)
#pragma unroll
      for (int p = 0; p < 2; ++p)
        a[r] += ev[r][p].x * uv[p].x + ev[r][p].y * uv[p].y + ev[r][p].z * uv[p].z +
                ev[r][p].w * uv[p].w;
  }
#pragma unroll
  for (int r = 0; r < 4; ++r)
#pragma unroll
    for (int off = 32; off > 0; off >>= 1) a[r] += __shfl_down(a[r], off, 64);
  if (lane == 0) {
#pragma unroll
    for (int r = 0; r < 4; ++r) {
      int row = row0 + r;
      sct[(row & 127) * 256 + (row >> 7)] = a[r];
    }
  }
}

// ---------------------------------------------------------------------------
// softmax over s per b; writes attn. sbuf: >=8 floats of LDS scratch.
// ---------------------------------------------------------------------------
__device__ __forceinline__ void softmax_body(int b, const float* __restrict__ sct,
                                             float* __restrict__ attn, float* sbuf) {
  float* wmax = sbuf;
  float* wsum = sbuf + 4;
  int t = threadIdx.x;
  int wave = t >> 6, lane = t & 63;
  float sc = sct[b * 256 + t];
  float m = sc;
#pragma unroll
  for (int off = 32; off > 0; off >>= 1) m = fmaxf(m, __shfl_xor(m, off, 64));
  if (lane == 0) wmax[wave] = m;
  __syncthreads();
  float m4 = fmaxf(fmaxf(wmax[0], wmax[1]), fmaxf(wmax[2], wmax[3]));
  float e = __expf(sc - m4);
  float s = e;
#pragma unroll
  for (int off = 32; off > 0; off >>= 1) s += __shfl_xor(s, off, 64);
  if (lane == 0) wsum[wave] = s;
  __syncthreads();
  float tot = (wsum[0] + wsum[1]) + (wsum[2] + wsum[3]);
  attn[b * 256 + t] = e / tot;
}

// ---------------------------------------------------------------------------
// context[b,h] = sum_s attn[b,s]*enc[s,b,h] -> bf16 into catin[:,1024+h]
// sm: >=256 floats of LDS scratch.
// ---------------------------------------------------------------------------
__device__ __forceinline__ void context_body(int blk, const float* __restrict__ enc,
                                             const float* __restrict__ attn,
                                             unsigned short* __restrict__ catin, float* sm) {
  int b = blk >> 2, hc = blk & 3;
  int t = threadIdx.x;
  __syncthreads();  // protect sm against previous job in this block
  sm[t] = attn[b * 256 + t];
  __syncthreads();
  int h = hc * 256 + t;
  const float* ep = enc + (size_t)b * 1024 + h;
  float a[16];
#pragma unroll
  for (int i = 0; i < 16; ++i) a[i] = 0.f;
  for (int s0 = 0; s0 < 256; s0 += 16)
#pragma unroll
    for (int i = 0; i < 16; ++i) a[i] += sm[s0 + i] * ep[(size_t)(s0 + i) * 131072];
  float tot = 0.f;
#pragma unroll
  for (int i = 0; i < 16; ++i) tot += a[i];
  catin[(size_t)b * 2048 + 1024 + h] = f2bf(tot);
}

// ---------------------------------------------------------------------------
// GRU gate: sums the 2 K-split partials of gi/gh; writes h fp32 + bf16 copy
// ---------------------------------------------------------------------------
__device__ __forceinline__ void gate_body(int b, const float* __restrict__ gi,
                                          const float* __restrict__ gh,
                                          const float* __restrict__ h_prev,
                                          float* __restrict__ h_out,
                                          unsigned short* __restrict__ h_bf, int bf_ld) {
  constexpr int SEG = 393216;
  int j = threadIdx.x * 4;
  const float* gib = gi + (size_t)b * 3072;
  const float* ghb = gh + (size_t)b * 3072;
  f32x4 ir = *(const f32x4*)(gib + j) + *(const f32x4*)(gib + SEG + j);
  f32x4 iz = *(const f32x4*)(gib + 1024 + j) + *(const f32x4*)(gib + SEG + 1024 + j);
  f32x4 in_ = *(const f32x4*)(gib + 2048 + j) + *(const f32x4*)(gib + SEG + 2048 + j);
  f32x4 hr = *(const f32x4*)(ghb + j) + *(const f32x4*)(ghb + SEG + j);
  f32x4 hz = *(const f32x4*)(ghb + 1024 + j) + *(const f32x4*)(ghb + SEG + 1024 + j);
  f32x4 hn = *(const f32x4*)(ghb + 2048 + j) + *(const f32x4*)(ghb + SEG + 2048 + j);
  f32x4 hp = *(const f32x4*)(h_prev + (size_t)b * 1024 + j);
  f32x4 ho;
#pragma unroll
  for (int c = 0; c < 4; ++c) {
    float r = 1.f / (1.f + __expf(-(ir[c] + hr[c])));
    float z = 1.f / (1.f + __expf(-(iz[c] + hz[c])));
    float n = tanhf(in_[c] + r * hn[c]);
    ho[c] = (1.f - z) * n + z * hp[c];
  }
  *(f32x4*)(h_out + (size_t)b * 1024 + j) = ho;
  uint2 pk{pack2(ho.x, ho.y), pack2(ho.z, ho.w)};
  *(uint2*)(h_bf + (size_t)b * bf_ld + j) = pk;
}

// ---------------------------------------------------------------------------
// cat_fix: sum 4 K-split partials (bias already in seg0), tanh, bf16
// ---------------------------------------------------------------------------
__device__ __forceinline__ void catfix_body(int m, const float* __restrict__ part,
                                            unsigned short* __restrict__ catbf) {
  int j = threadIdx.x * 4;
  const float* p = part + (size_t)m * 1024 + j;
  f32x4 s = *(const f32x4*)p + *(const f32x4*)(p + 131072) + *(const f32x4*)(p + 262144) +
            *(const f32x4*)(p + 393216);
  f32x4 o;
#pragma unroll
  for (int c = 0; c < 4; ++c) o[c] = tanhf(s[c]);
  uint2 pk{pack2(o.x, o.y), pack2(o.z, o.w)};
  *(uint2*)(catbf + (size_t)m * 1024 + j) = pk;
}

// ---------------------------------------------------------------------------
// The whole decoder as ONE kernel with grid-wide barriers between stages.
// Grid-stride loops keep every stage's natural job decomposition.
// ---------------------------------------------------------------------------
struct MegaP {
  const int* ids;
  const float *hidden, *enc, *embed, *W_attn, *v;
  const float *w_ih0, *w_hh0, *b_ih0, *b_hh0;
  const float *w_ih1, *w_hh1, *b_ih1, *b_hh1;
  const float *W_cat, *b_cat, *W_out, *b_out;
  float *out, *h0, *h1, *attn;
  float *gi, *gh, *u2, *sct, *catp;
  unsigned short *A0, *Hh0, *Hh1, *h0bf, *catin, *catbf;
  unsigned* bar;
};

__global__ __launch_bounds__(256, 4) void mega(MegaP p) {
  // LDS pool: 2*128*64 + 2*32*64 shorts = 40960 B (fits 4 blocks/CU exactly).
  __shared__ unsigned short s_a[2 * 128 * 64];
  __shared__ unsigned short s_w[2 * 32 * 64];
  const int nblk = gridDim.x;
  const int bid = blockIdx.x;

  // S0: bf16 prep (384) + u2 precompute (128)
  for (int j = bid; j < 512; j += nblk) {
    if (j < 384) prep_body(j, p.ids, p.hidden, p.embed, p.A0, p.Hh0, p.Hh1);
    else u2_body(j - 384, p.W_attn, p.v, p.u2);
  }
  grid_barrier(p.bar, 1, nblk);

  // S1: GRU layer-0 GEMM (768) + scores (2048)
  for (int j = bid; j < 2816; j += nblk) {
    if (j < 768) {
      int bx = j % 192, by = (j / 192) & 1, bz = j / 384;
      GemmArgs g{by ? p.Hh0 : p.A0, by ? p.w_hh0 : p.w_ih0, by ? p.b_hh0 : p.b_ih0,
                 by ? p.gh : p.gi};
      gemm_body<16, 4, 1>(g, bx, bz, 1024, 1024, 3072, 512, 393216, s_a, s_w);
    } else {
      scores_body(j - 768, p.enc, p.u2, p.sct);
    }
  }
  grid_barrier(p.bar, 2, nblk);

  // S2: gate0 (128) + softmax (128)
  for (int j = bid; j < 256; j += nblk) {
    if (j < 128) gate_body(j, p.gi, p.gh, p.hidden, p.h0, p.h0bf, 1024);
    else softmax_body(j - 128, p.sct, p.attn, (float*)s_w);
  }
  grid_barrier(p.bar, 3, nblk);

  // S3: GRU layer-1 GEMM (768) + context (512)
  for (int j = bid; j < 1280; j += nblk) {
    if (j < 768) {
      int bx = j % 192, by = (j / 192) & 1, bz = j / 384;
      GemmArgs g{by ? p.Hh1 : p.h0bf, by ? p.w_hh1 : p.w_ih1, by ? p.b_hh1 : p.b_ih1,
                 by ? p.gh : p.gi};
      gemm_body<16, 4, 1>(g, bx, bz, 1024, 1024, 3072, 512, 393216, s_a, s_w);
    } else {
      context_body(j - 768, p.enc, p.attn, p.catin, (float*)s_a);
    }
  }
  grid_barrier(p.bar, 4, nblk);

  // S4: gate1 (128) — writes h1 + catin left half
  for (int j = bid; j < 128; j += nblk)
    gate_body(j, p.gi, p.gh, p.hidden + 131072, p.h1, p.catin, 2048);
  grid_barrier(p.bar, 5, nblk);

  // S5: concat GEMM (64 x 4 split-K)
  for (int j = bid; j < 256; j += nblk) {
    GemmArgs g{p.catin, p.W_cat, p.b_cat, p.catp};
    gemm_body<16, 4, 1>(g, j % 64, j / 64, 2048, 2048, 1024, 512, 131072, s_a, s_w);
  }
  grid_barrier(p.bar, 6, nblk);

  // S6: cat_fix (128)
  for (int j = bid; j < 128; j += nblk) catfix_body(j, p.catp, p.catbf);
  grid_barrier(p.bar, 7, nblk);

  // S7: output GEMM (1000)
  for (int j = bid; j < 1000; j += nblk) {
    GemmArgs g{p.catbf, p.W_out, p.b_out, p.out};
    gemm_body<32, 2, 2>(g, j, 0, 1024, 1024, 32000, 1024, 0, s_a, s_w);
  }
}

// ---------------------------------------------------------------------------
extern "C" void kernel_launch(void* const* d_in, const int* in_sizes, int n_in,
                              void* d_out_, int out_size, void* d_ws, size_t ws_size,
                              hipStream_t stream) {
  float* out = (float*)d_out_;
  float* ws = (float*)d_ws;

  MegaP p;
  p.ids = (const int*)d_in[0];
  p.hidden = (const float*)d_in[1];
  p.enc = (const float*)d_in[2];
  p.embed = (const float*)d_in[3];
  p.W_attn = (const float*)d_in[4];
  p.v = (const float*)d_in[6];
  p.w_ih0 = (const float*)d_in[7];
  p.w_hh0 = (const float*)d_in[8];
  p.b_ih0 = (const float*)d_in[9];
  p.b_hh0 = (const float*)d_in[10];
  p.w_ih1 = (const float*)d_in[11];
  p.w_hh1 = (const float*)d_in[12];
  p.b_ih1 = (const float*)d_in[13];
  p.b_hh1 = (const float*)d_in[14];
  p.W_cat = (const float*)d_in[15];
  p.b_cat = (const float*)d_in[16];
  p.W_out = (const float*)d_in[17];
  p.b_out = (const float*)d_in[18];

  p.out = out;
  p.h0 = out + 4096000;
  p.h1 = out + 4227072;
  p.attn = out + 4358144;

  p.gi = ws;                      // 2 x 393216
  p.gh = ws + 786432;             // 2 x 393216
  p.u2 = ws + 1572864;            // 1024
  p.sct = ws + 1573888;           // 32768
  p.catp = ws + 1606656;          // 4 x 131072
  unsigned short* bfb = (unsigned short*)(ws + 2130944);
  p.A0 = bfb;                     // 131072
  p.Hh0 = bfb + 131072;
  p.Hh1 = bfb + 262144;
  p.h0bf = bfb + 393216;
  p.catin = bfb + 524288;         // 128 x 2048
  p.catbf = bfb + 786432;         // 128 x 1024
  p.bar = (unsigned*)(ws + 4000000);  // barrier counter, well past used region

  // Grid sized to guaranteed co-residency (grid-stride loops tolerate any size).
  static int nblk = 0;
  if (nblk == 0) {
    int mb = 0;
    if (hipOccupancyMaxActiveBlocksPerMultiprocessor(&mb, mega, 256, 0) != hipSuccess || mb < 1)
      mb = 1;
    long g = 256L * mb;
    nblk = (int)(g > 1024 ? 1024 : g);
  }

  hipMemsetAsync(p.u2, 0, 1024 * sizeof(float), stream);
  hipMemsetAsync(p.bar, 0, sizeof(unsigned), stream);
  mega<<<nblk, 256, 0, stream>>>(p);
}